// Round 1
// baseline (1051.873 us; speedup 1.0000x reference)
//
#include <hip/hip_runtime.h>

#define N_EDGES 800000
#define ATOM 128
#define BOND 64
#define KDIM 192
#define MSG 256
#define LDA 208          // padded A-tile row stride (bf16 elems): 416 B = 104 words; 104%32=8 -> optimal bank spread
#define MTILES (N_EDGES / 64)   // 12500
#define MGROUPS 512

typedef short bf16x8 __attribute__((ext_vector_type(8)));
typedef float f32x4 __attribute__((ext_vector_type(4)));
typedef unsigned short u16x4 __attribute__((ext_vector_type(4)));

__device__ __forceinline__ unsigned short f2bf(float x) {
    // round-to-nearest-even f32 -> bf16 (inputs are finite; no NaN handling needed)
    unsigned u = __float_as_uint(x);
    unsigned r = u + 0x7fffu + ((u >> 16) & 1u);
    return (unsigned short)(r >> 16);
}

__device__ __forceinline__ u16x4 cvt4(float4 v) {
    u16x4 h;
    h[0] = f2bf(v.x); h[1] = f2bf(v.y); h[2] = f2bf(v.z); h[3] = f2bf(v.w);
    return h;
}

__global__ __launch_bounds__(256, 2)
void bond_msg_kernel(const float* __restrict__ V,
                     const float* __restrict__ E,
                     const int* __restrict__ eidx,     // row 0 = sources
                     const float* __restrict__ W,      // [256][192] row-major
                     const float* __restrict__ b,
                     float* __restrict__ out)          // [800000][256]
{
    __shared__ unsigned short Atile[64 * LDA];
    __shared__ int srcS[64];

    const int tid   = threadIdx.x;
    const int lane  = tid & 63;
    const int wid   = tid >> 6;
    const int quad  = lane >> 4;
    const int l16   = lane & 15;
    const int wave_m = wid >> 1;               // 0..1 -> m offset *32
    const int wave_n = wid & 1;                // 0..1 -> n offset *64
    const int n0    = (blockIdx.x & 1) * 128;  // which 128-col half
    const int mgrp  = blockIdx.x >> 1;         // 0..511

    // ---------- B operand: W rows -> bf16 fragments, in registers, once per block.
    // B[k][n] = W[n][k]; lane holds n = nbase+ni*16, k = ks*32 + quad*8 + j (j=0..7, contiguous).
    const int nbase = n0 + wave_n * 64 + l16;
    bf16x8 bfrag[6][4];
    float bias[4];
#pragma unroll
    for (int ni = 0; ni < 4; ni++) {
        bias[ni] = b[nbase + ni * 16];
        const float* wr = W + (nbase + ni * 16) * KDIM;
#pragma unroll
        for (int ks = 0; ks < 6; ks++) {
            const float* p = wr + ks * 32 + quad * 8;
            float4 f0 = *(const float4*)p;
            float4 f1 = *(const float4*)(p + 4);
            bf16x8 t;
            t[0] = (short)f2bf(f0.x); t[1] = (short)f2bf(f0.y);
            t[2] = (short)f2bf(f0.z); t[3] = (short)f2bf(f0.w);
            t[4] = (short)f2bf(f1.x); t[5] = (short)f2bf(f1.y);
            t[6] = (short)f2bf(f1.z); t[7] = (short)f2bf(f1.w);
            bfrag[ks][ni] = t;
        }
    }

    // ---------- persistent loop over 64-edge M-tiles
    for (int mt = mgrp; mt < MTILES; mt += MGROUPS) {
        const long e0 = (long)mt * 64;

        __syncthreads();   // previous tile's LDS reads done
        if (tid < 64) srcS[tid] = eidx[e0 + tid];
        __syncthreads();

        // V part: 64 edges x 128 f32 -> bf16; 2048 float4 chunks, 8/thread
#pragma unroll
        for (int c = 0; c < 8; c++) {
            int cc = tid + c * 256;
            int m  = cc >> 5;            // edge within tile
            int fo = (cc & 31) << 2;     // float offset 0..124
            float4 v = *(const float4*)(V + (long)srcS[m] * ATOM + fo);
            *(u16x4*)&Atile[m * LDA + fo] = cvt4(v);
        }
        // E part: 64 edges x 64 f32 -> bf16; 1024 float4 chunks, 4/thread
#pragma unroll
        for (int c = 0; c < 4; c++) {
            int cc = tid + c * 256;
            int m  = cc >> 4;
            int fo = (cc & 15) << 2;
            float4 ev = *(const float4*)(E + (e0 + m) * BOND + fo);
            *(u16x4*)&Atile[m * LDA + ATOM + fo] = cvt4(ev);
        }
        __syncthreads();

        // ---------- compute: wave tile 32 (m) x 64 (n), 6 K-steps
        f32x4 acc[2][4];
#pragma unroll
        for (int mi = 0; mi < 2; mi++)
#pragma unroll
            for (int ni = 0; ni < 4; ni++)
                acc[mi][ni] = (f32x4){0.f, 0.f, 0.f, 0.f};

        const int am = wave_m * 32 + l16;   // A operand: m = lane&15 (+16 for frag 1)
        const int ko = quad * 8;
#pragma unroll
        for (int ks = 0; ks < 6; ks++) {
            bf16x8 a0 = *(const bf16x8*)&Atile[am * LDA + ks * 32 + ko];
            bf16x8 a1 = *(const bf16x8*)&Atile[(am + 16) * LDA + ks * 32 + ko];
#pragma unroll
            for (int ni = 0; ni < 4; ni++) {
                acc[0][ni] = __builtin_amdgcn_mfma_f32_16x16x32_bf16(a0, bfrag[ks][ni], acc[0][ni], 0, 0, 0);
                acc[1][ni] = __builtin_amdgcn_mfma_f32_16x16x32_bf16(a1, bfrag[ks][ni], acc[1][ni], 0, 0, 0);
            }
        }

        // ---------- epilogue: D row = quad*4 + r, col = l16
#pragma unroll
        for (int mi = 0; mi < 2; mi++) {
            const long rowb = e0 + wave_m * 32 + mi * 16 + quad * 4;
#pragma unroll
            for (int ni = 0; ni < 4; ni++) {
                float* op = out + rowb * MSG + nbase + ni * 16;
#pragma unroll
                for (int r = 0; r < 4; r++)
                    op[(long)r * MSG] = acc[mi][ni][r] + bias[ni];
            }
        }
    }
}

extern "C" void kernel_launch(void* const* d_in, const int* in_sizes, int n_in,
                              void* d_out, int out_size, void* d_ws, size_t ws_size,
                              hipStream_t stream) {
    const float* V    = (const float*)d_in[0];
    const float* E    = (const float*)d_in[1];
    const int*   eidx = (const int*)d_in[2];
    const float* W    = (const float*)d_in[3];
    const float* b    = (const float*)d_in[4];
    float* out = (float*)d_out;

    dim3 grid(2 * MGROUPS), block(256);
    hipLaunchKernelGGL(bond_msg_kernel, grid, block, 0, stream, V, E, eidx, W, b, out);
}